// Round 7
// baseline (317.073 us; speedup 1.0000x reference)
//
#include <hip/hip_runtime.h>

// ======================= shared-scratch tiled GEMM body =======================
// C[m0+m, col0+n] = sum_k A[(m0+m)*lda + k] * B[k*ldb + col0 + n]
// 64 rows x 128 cols per block, 256 threads, 8x4 register tile. smem: 3200 floats.
__device__ __forceinline__ void gemm_body(
    float* __restrict__ smem,
    const float* __restrict__ A, int lda,
    const float* __restrict__ B, int ldb,
    float* __restrict__ C, int ldc, int K,
    int m0, int col0) {
  float* As = smem;            // [16][68]
  float* Bs = smem + 16 * 68;  // [16][132]
  const int t = threadIdx.x;
  const int tn = t & 31, tm = t >> 5;
  const int lam = t >> 2, lak = (t & 3) * 4;
  const int lbk = t >> 4, lbn = (t & 15) * 8;
  float acc[8][4];
#pragma unroll
  for (int i = 0; i < 8; ++i)
#pragma unroll
    for (int j = 0; j < 4; ++j) acc[i][j] = 0.f;
  for (int k0 = 0; k0 < K; k0 += 16) {
    float4 av = *reinterpret_cast<const float4*>(A + (size_t)(m0 + lam) * lda + k0 + lak);
    As[(lak + 0) * 68 + lam] = av.x;
    As[(lak + 1) * 68 + lam] = av.y;
    As[(lak + 2) * 68 + lam] = av.z;
    As[(lak + 3) * 68 + lam] = av.w;
    const float* bp = B + (size_t)(k0 + lbk) * ldb + col0 + lbn;
    float4 b0 = *reinterpret_cast<const float4*>(bp);
    float4 b1 = *reinterpret_cast<const float4*>(bp + 4);
    float* bd = &Bs[lbk * 132 + lbn];
    bd[0] = b0.x; bd[1] = b0.y; bd[2] = b0.z; bd[3] = b0.w;
    bd[4] = b1.x; bd[5] = b1.y; bd[6] = b1.z; bd[7] = b1.w;
    __syncthreads();
#pragma unroll
    for (int kk = 0; kk < 16; ++kk) {
      float4 a0 = *reinterpret_cast<const float4*>(&As[kk * 68 + tm * 8]);
      float4 a1 = *reinterpret_cast<const float4*>(&As[kk * 68 + tm * 8 + 4]);
      float4 bv = *reinterpret_cast<const float4*>(&Bs[kk * 132 + tn * 4]);
      float a[8] = {a0.x, a0.y, a0.z, a0.w, a1.x, a1.y, a1.z, a1.w};
      float b[4] = {bv.x, bv.y, bv.z, bv.w};
#pragma unroll
      for (int i = 0; i < 8; ++i)
#pragma unroll
        for (int j = 0; j < 4; ++j) acc[i][j] = fmaf(a[i], b[j], acc[i][j]);
    }
    __syncthreads();
  }
#pragma unroll
  for (int i = 0; i < 8; ++i) {
    float* cp = C + (size_t)(m0 + tm * 8 + i) * ldc + col0 + tn * 4;
    *reinterpret_cast<float4*>(cp) =
        make_float4(acc[i][0], acc[i][1], acc[i][2], acc[i][3]);
  }
}

// ============ small GAT attend: FIN=128, TPR=32, global src -> out ptr ========
// wn/ws are per-lane weight fragments at f0=(t&31)*4. scratch: (E+1)*165+... floats.
template <int E>
__device__ __forceinline__ void gat_small(
    float* __restrict__ scratch,
    const float* __restrict__ xself, const float* __restrict__ xneigh,
    const float4* __restrict__ wn, const float4* __restrict__ ws,
    float* __restrict__ out) {
  constexpr int FIN = 128, MR = E + 1, RPP = 8, PSTR = 33, G = 8;
  float* tile = scratch;                // MR*128
  float* partial = tile + MR * FIN;     // MR*33
  float* logitS = partial + MR * PSTR;  // MR*4
  float* alpha = logitS + MR * 4;       // E*4
  const int t = threadIdx.x;
  const int el = t >> 5;
  const int f0 = (t & 31) * 4;
#pragma unroll
  for (int p = 0; p * RPP < MR; ++p) {
    int e = p * RPP + el;
    if (e < MR) {
      const float* src = (e < E) ? (xneigh + (size_t)e * FIN + f0) : (xself + f0);
      float4 x = *reinterpret_cast<const float4*>(src);
      *reinterpret_cast<float4*>(tile + e * FIN + f0) = x;
      float ph[4];
#pragma unroll
      for (int h = 0; h < 4; ++h) {
        float4 w = (e < E) ? wn[h] : ws[h];
        ph[h] = x.x * w.x + x.y * w.y + x.z * w.z + x.w * w.w;
      }
#pragma unroll
      for (int h = 0; h < 4; ++h) {  // quad reduce (DPP)
        ph[h] += __shfl_xor(ph[h], 1);
        ph[h] += __shfl_xor(ph[h], 2);
      }
      if ((t & 3) == 0) {
        *reinterpret_cast<float4*>(partial + e * PSTR + ((t & 31) >> 2) * 4) =
            make_float4(ph[0], ph[1], ph[2], ph[3]);
      }
    }
  }
  __syncthreads();
  if (t < MR * 4) {
    int e = t >> 2, h = t & 3;
    float v = 0.f;
#pragma unroll
    for (int g = 0; g < G; ++g) v += partial[e * PSTR + g * 4 + h];
    logitS[t] = v;
  }
  __syncthreads();
  if (t < 4) {
    const float es = logitS[E * 4 + t];
    float m = -1e30f;
#pragma unroll
    for (int e = 0; e < E; ++e) {
      float x = es + logitS[e * 4 + t];
      x = (x > 0.f) ? x : 0.2f * x;  // LeakyReLU(0.2)
      m = fmaxf(m, x);
    }
    float s = 0.f;
#pragma unroll
    for (int e = 0; e < E; ++e) {
      float x = es + logitS[e * 4 + t];
      x = (x > 0.f) ? x : 0.2f * x;
      float p = __expf(x - m);
      alpha[e * 4 + t] = p;
      s += p;
    }
    float inv = 1.f / s;
#pragma unroll
    for (int e = 0; e < E; ++e) alpha[e * 4 + t] *= inv;
  }
  __syncthreads();
  if (t < 128) {
    int h = t >> 5, f = (t & 31) * 4;
    float4 acc = make_float4(0.f, 0.f, 0.f, 0.f);
#pragma unroll
    for (int e = 0; e < E; ++e) {
      float a = alpha[e * 4 + h];
      float4 x = *reinterpret_cast<const float4*>(tile + e * FIN + f);
      acc.x = fmaf(a, x.x, acc.x);
      acc.y = fmaf(a, x.y, acc.y);
      acc.z = fmaf(a, x.z, acc.z);
      acc.w = fmaf(a, x.w, acc.w);
    }
    *reinterpret_cast<float4*>(out + h * FIN + f) = acc;
  }
}

// ====== prepA: T gemm (64) + wa0 (4) + va direct 2-stage (16) — no deps ======
__global__ void __launch_bounds__(256) prepA(
    const float* __restrict__ W0, const float* __restrict__ a0s,
    const float* __restrict__ a0n,
    const float* __restrict__ W1, const float* __restrict__ a1s,
    const float* __restrict__ a1n, const float* __restrict__ Wfc,
    float* __restrict__ wa0s, float* __restrict__ wa0n,
    float* __restrict__ va1s, float* __restrict__ va1n,
    float* __restrict__ T) {
  __shared__ float smem[3200];
  const int b = blockIdx.x;
  const int t = threadIdx.x;
  if (b < 64) {
    // T[h][k][o] = sum_m W1[k, h*128+m] * Wfc[h*128+m, o]; M=512,K=128,N=256
    int h = b >> 4, mb = (b >> 1) & 7, nb = b & 1;
    gemm_body(smem, W1 + h * 128, 512, Wfc + (size_t)h * 32768, 256,
              T + (size_t)h * 131072, 256, 128, mb * 64, nb * 128);
    return;
  }
  if (b < 68) {
    // wa0[h*128+f] = sum_d W0[f, h*128+d] * a0[h,d]
    int idx = (b - 64) * 256 + t;
    const float* a = (idx < 512) ? a0s : a0n;
    float* dst = (idx < 512) ? wa0s : wa0n;
    int i = idx & 511;
    int f = i >> 2, h = i & 3;
    const float* wrow = W0 + (size_t)f * 512 + h * 128;
    const float* arow = a + h * 128;
    float v = 0.f;
#pragma unroll 8
    for (int d = 0; d < 128; ++d) v = fmaf(wrow[d], arow[d], v);
    dst[h * 128 + f] = v;
    return;
  }
  // va direct: stage1 wa1 slice in LDS, stage2 contract with W0.
  // va[h*512 + h0b*128 + f] = sum_n W0[f, h0b*128+n] * (sum_d W1[h0b*128+n, h*128+d]*a1[h,d])
  int v = b - 68;  // 0..15
  int sel = v >> 3, h = (v >> 1) & 3, hp = v & 1;
  const float* a1 = sel ? a1n : a1s;
  float* dst = sel ? va1n : va1s;
  int h0b = hp * 2 + (t >> 7);
  float* ws1 = smem;  // [256]
  {
    int n = t & 127;
    const float* w1row = W1 + (size_t)(h0b * 128 + n) * 512 + h * 128;
    const float* arow = a1 + h * 128;
    float s = 0.f;
#pragma unroll 8
    for (int d = 0; d < 128; ++d) s = fmaf(w1row[d], arow[d], s);
    ws1[t] = s;
  }
  __syncthreads();
  {
    int f = t & 127;
    const float* w0row = W0 + (size_t)f * 512 + h0b * 128;
    const float* wsl = ws1 + (t >> 7) * 128;
    float s = 0.f;
#pragma unroll 8
    for (int n = 0; n < 128; ++n) s = fmaf(w0row[n], wsl[n], s);
    dst[h * 512 + h0b * 128 + f] = s;
  }
}

// ========== subtree: Wfinal gemm (64) + per-b full GAT subtree (1024) =========
// Each subtree block: 10x attend(E=25) + attend(E=10) into LDS xaggL, then
// layer-1 attend in place on xaggL -> aggx[b]. No level-1 global round-trip.
__global__ void __launch_bounds__(256, 4) subtree(
    const float* __restrict__ h0, const float* __restrict__ h1,
    const float* __restrict__ h2,
    const float* __restrict__ wa0s, const float* __restrict__ wa0n,
    const float* __restrict__ va1s, const float* __restrict__ va1n,
    const float* __restrict__ W0, const float* __restrict__ T,
    float* __restrict__ Wfinal, float* __restrict__ aggx) {
  __shared__ float smem[10022];  // xaggL 5632 + max(E25:4390, L1:1503)
  const int b0 = blockIdx.x;
  const int t = threadIdx.x;
  if (b0 < 64) {
    // Wfinal[h][(h0b*128+f)][o] = sum_n W0[f, h0b*128+n] * T[h][h0b*128+n][o]
    int g = b0;
    int pair = g >> 2, mb = (g >> 1) & 1, nb = g & 1;
    int h = pair >> 2, h0b = pair & 3;
    gemm_body(smem, W0 + h0b * 128, 512,
              T + (size_t)h * 131072 + (size_t)h0b * 32768, 256,
              Wfinal + (size_t)h * 131072 + (size_t)h0b * 32768, 256, 128,
              mb * 64, nb * 128);
    return;
  }
  const int b = b0 - 64;
  float* xaggL = smem;            // [11][512]: rows 0..9 = children, row 10 = self
  float* scratch = smem + 5632;
  {
    const int f0 = (t & 31) * 4;
    float4 wn[4], ws4[4];
#pragma unroll
    for (int h = 0; h < 4; ++h) {
      wn[h] = *reinterpret_cast<const float4*>(wa0n + h * 128 + f0);
      ws4[h] = *reinterpret_cast<const float4*>(wa0s + h * 128 + f0);
    }
    // level-0 self: E=10 over h1 rows, self h0[b] -> xaggL row 10
    gat_small<10>(scratch, h0 + (size_t)b * 128, h1 + (size_t)b * 1280,
                  wn, ws4, xaggL + 10 * 512);
    __syncthreads();
    // children c: E=25 over h2 rows, self h1[b*10+c] -> xaggL row c
#pragma unroll 1
    for (int c = 0; c < 10; ++c) {
      gat_small<25>(scratch, h1 + (size_t)(b * 10 + c) * 128,
                    h2 + (size_t)(b * 10 + c) * 3200, wn, ws4, xaggL + c * 512);
      __syncthreads();
    }
  }
  // layer-1 attend in place: FIN=512, E=10, tile = xaggL
  {
    constexpr int PSTR = 129;
    float* partial = scratch;            // 11*129
    float* logitS = partial + 11 * PSTR; // 44
    float* alpha = logitS + 44;          // 40
    const int el = t >> 7;
    const int f0 = (t & 127) * 4;
    float4 vn[4], vs4[4];
#pragma unroll
    for (int h = 0; h < 4; ++h) {
      vn[h] = *reinterpret_cast<const float4*>(va1n + h * 512 + f0);
      vs4[h] = *reinterpret_cast<const float4*>(va1s + h * 512 + f0);
    }
#pragma unroll
    for (int p = 0; p < 6; ++p) {
      int e = p * 2 + el;
      if (e < 11) {
        float4 x = *reinterpret_cast<const float4*>(xaggL + e * 512 + f0);
        float ph[4];
#pragma unroll
        for (int h = 0; h < 4; ++h) {
          float4 w = (e < 10) ? vn[h] : vs4[h];
          ph[h] = x.x * w.x + x.y * w.y + x.z * w.z + x.w * w.w;
        }
#pragma unroll
        for (int h = 0; h < 4; ++h) {
          ph[h] += __shfl_xor(ph[h], 1);
          ph[h] += __shfl_xor(ph[h], 2);
        }
        if ((t & 3) == 0) {
          *reinterpret_cast<float4*>(partial + e * PSTR + ((t & 127) >> 2) * 4) =
              make_float4(ph[0], ph[1], ph[2], ph[3]);
        }
      }
    }
    __syncthreads();
    if (t < 44) {
      int e = t >> 2, h = t & 3;
      float v = 0.f;
#pragma unroll
      for (int g = 0; g < 32; ++g) v += partial[e * PSTR + g * 4 + h];
      logitS[t] = v;
    }
    __syncthreads();
    if (t < 4) {
      const float es = logitS[10 * 4 + t];
      float m = -1e30f;
#pragma unroll
      for (int e = 0; e < 10; ++e) {
        float x = es + logitS[e * 4 + t];
        x = (x > 0.f) ? x : 0.2f * x;
        m = fmaxf(m, x);
      }
      float s = 0.f;
#pragma unroll
      for (int e = 0; e < 10; ++e) {
        float x = es + logitS[e * 4 + t];
        x = (x > 0.f) ? x : 0.2f * x;
        float p = __expf(x - m);
        alpha[e * 4 + t] = p;
        s += p;
      }
      float inv = 1.f / s;
#pragma unroll
      for (int e = 0; e < 10; ++e) alpha[e * 4 + t] *= inv;
    }
    __syncthreads();
    float* outb = aggx + (size_t)b * 2048;
    for (int o = t; o < 512; o += 256) {  // 512 float4 units
      int h = o >> 7, f = (o & 127) * 4;
      float4 acc = make_float4(0.f, 0.f, 0.f, 0.f);
#pragma unroll
      for (int e = 0; e < 10; ++e) {
        float a = alpha[e * 4 + h];
        float4 x = *reinterpret_cast<const float4*>(xaggL + e * 512 + f);
        acc.x = fmaf(a, x.x, acc.x);
        acc.y = fmaf(a, x.y, acc.y);
        acc.z = fmaf(a, x.z, acc.z);
        acc.w = fmaf(a, x.w, acc.w);
      }
      *reinterpret_cast<float4*>(outb + h * 512 + f) = acc;
    }
  }
}

// ======================= tail: K-split GEMM + reduce ==========================
__global__ void __launch_bounds__(256) gemm_ksplit(
    const float* __restrict__ A, const float* __restrict__ B,
    float* __restrict__ Cpart) {
  __shared__ float smem[3200];
  const int ks = blockIdx.z;
  gemm_body(smem, A + ks * 256, 2048, B + (size_t)ks * 65536, 256,
            Cpart + (size_t)ks * 262144, 256, 256, blockIdx.x * 64,
            blockIdx.y * 128);
}

__global__ void __launch_bounds__(256) reduce8(
    const float* __restrict__ Cpart, float* __restrict__ out) {
  int i = blockIdx.x * 256 + threadIdx.x;  // float4 index, 65536 total
  const float4* p = reinterpret_cast<const float4*>(Cpart) + i;
  float4 s = p[0];
#pragma unroll
  for (int ks = 1; ks < 8; ++ks) {
    float4 v = p[(size_t)ks * 65536];
    s.x += v.x; s.y += v.y; s.z += v.z; s.w += v.w;
  }
  reinterpret_cast<float4*>(out)[i] = s;
}

extern "C" void kernel_launch(void* const* d_in, const int* in_sizes, int n_in,
                              void* d_out, int out_size, void* d_ws, size_t ws_size,
                              hipStream_t stream) {
  const float* h0  = (const float*)d_in[0];
  const float* h1  = (const float*)d_in[1];
  const float* h2  = (const float*)d_in[2];
  const float* W0  = (const float*)d_in[3];
  const float* a0s = (const float*)d_in[4];
  const float* a0n = (const float*)d_in[5];
  const float* W1  = (const float*)d_in[6];
  const float* a1s = (const float*)d_in[7];
  const float* a1n = (const float*)d_in[8];
  const float* Wfc = (const float*)d_in[9];
  float* out = (float*)d_out;

  float* ws = (float*)d_ws;
  float* wa0s   = ws;                  // [4][128]
  float* wa0n   = wa0s + 512;          // [4][128]
  float* va1s   = wa0n + 512;          // [4][512]
  float* va1n   = va1s + 2048;         // [4][512]
  float* T      = va1n + 2048;         // [4][512][256] = 524288
  float* Wfinal = T + 524288;          // [4][512][256] = 524288
  float* aggx   = Wfinal + 524288;     // [1024][2048]  = 2097152
  float* Cpart  = aggx + 2097152;      // [8][1024][256]= 2097152
  // total ~5.25M floats = 21 MB

  prepA<<<84, 256, 0, stream>>>(W0, a0s, a0n, W1, a1s, a1n, Wfc,
                                wa0s, wa0n, va1s, va1n, T);
  subtree<<<1088, 256, 0, stream>>>(h0, h1, h2, wa0s, wa0n, va1s, va1n,
                                    W0, T, Wfinal, aggx);
  gemm_ksplit<<<dim3(16, 2, 8), 256, 0, stream>>>(aggx, Wfinal, Cpart);
  reduce8<<<256, 256, 0, stream>>>(Cpart, out);
}

// Round 8
// 270.865 us; speedup vs baseline: 1.1706x; 1.1706x over previous
//
#include <hip/hip_runtime.h>

// ======================= shared-scratch tiled GEMM body =======================
// C[m0+m, col0+n] = sum_k A[(m0+m)*lda + k] * B[k*ldb + col0 + n]
// 64 rows x 128 cols per block, 256 threads, 8x4 register tile.
// smem needs 16*68 + 16*132 = 3200 floats.
__device__ __forceinline__ void gemm_body(
    float* __restrict__ smem,
    const float* __restrict__ A, int lda,
    const float* __restrict__ B, int ldb,
    float* __restrict__ C, int ldc, int K,
    int m0, int col0) {
  float* As = smem;            // [16][68]
  float* Bs = smem + 16 * 68;  // [16][132]
  const int t = threadIdx.x;
  const int tn = t & 31, tm = t >> 5;
  const int lam = t >> 2, lak = (t & 3) * 4;
  const int lbk = t >> 4, lbn = (t & 15) * 8;
  float acc[8][4];
#pragma unroll
  for (int i = 0; i < 8; ++i)
#pragma unroll
    for (int j = 0; j < 4; ++j) acc[i][j] = 0.f;
  for (int k0 = 0; k0 < K; k0 += 16) {
    float4 av = *reinterpret_cast<const float4*>(A + (size_t)(m0 + lam) * lda + k0 + lak);
    As[(lak + 0) * 68 + lam] = av.x;
    As[(lak + 1) * 68 + lam] = av.y;
    As[(lak + 2) * 68 + lam] = av.z;
    As[(lak + 3) * 68 + lam] = av.w;
    const float* bp = B + (size_t)(k0 + lbk) * ldb + col0 + lbn;
    float4 b0 = *reinterpret_cast<const float4*>(bp);
    float4 b1 = *reinterpret_cast<const float4*>(bp + 4);
    float* bd = &Bs[lbk * 132 + lbn];
    bd[0] = b0.x; bd[1] = b0.y; bd[2] = b0.z; bd[3] = b0.w;
    bd[4] = b1.x; bd[5] = b1.y; bd[6] = b1.z; bd[7] = b1.w;
    __syncthreads();
#pragma unroll
    for (int kk = 0; kk < 16; ++kk) {
      float4 a0 = *reinterpret_cast<const float4*>(&As[kk * 68 + tm * 8]);
      float4 a1 = *reinterpret_cast<const float4*>(&As[kk * 68 + tm * 8 + 4]);
      float4 bv = *reinterpret_cast<const float4*>(&Bs[kk * 132 + tn * 4]);
      float a[8] = {a0.x, a0.y, a0.z, a0.w, a1.x, a1.y, a1.z, a1.w};
      float b[4] = {bv.x, bv.y, bv.z, bv.w};
#pragma unroll
      for (int i = 0; i < 8; ++i)
#pragma unroll
        for (int j = 0; j < 4; ++j) acc[i][j] = fmaf(a[i], b[j], acc[i][j]);
    }
    __syncthreads();
  }
#pragma unroll
  for (int i = 0; i < 8; ++i) {
    float* cp = C + (size_t)(m0 + tm * 8 + i) * ldc + col0 + tn * 4;
    *reinterpret_cast<float4*>(cp) =
        make_float4(acc[i][0], acc[i][1], acc[i][2], acc[i][3]);
  }
}

// ======================= GAT attention body (compile-time E) ==================
// softmax over E neighbors, aggregate in input space; wa in registers.
// smem floats needed: (E+1)*FIN + (E+1)*(TPR+1) + (E+1)*4 + E*4.
template <int FIN, int TPR, int E>
__device__ __forceinline__ void gat_body(
    float* __restrict__ smem,
    const float* __restrict__ xself, const float* __restrict__ xneigh,
    const float* __restrict__ waS, const float* __restrict__ waN,
    float* __restrict__ out) {
  constexpr int MR = E + 1;
  constexpr int RPP = 256 / TPR;
  constexpr int PSTR = TPR + 1;
  constexpr int G = TPR / 4;
  float* tile = smem;                   // MR*FIN
  float* partial = tile + MR * FIN;     // MR*PSTR
  float* logitS = partial + MR * PSTR;  // MR*4
  float* alpha = logitS + MR * 4;       // E*4
  const int t = threadIdx.x;
  const int el = t / TPR;
  const int f0 = (t % TPR) * 4;
  float4 wn[4], ws[4];
#pragma unroll
  for (int h = 0; h < 4; ++h) {
    wn[h] = *reinterpret_cast<const float4*>(waN + h * FIN + f0);
    ws[h] = *reinterpret_cast<const float4*>(waS + h * FIN + f0);
  }
#pragma unroll
  for (int p = 0; p * RPP < MR; ++p) {
    int e = p * RPP + el;
    if (e < MR) {
      const float* src = (e < E) ? (xneigh + (size_t)e * FIN + f0) : (xself + f0);
      float4 x = *reinterpret_cast<const float4*>(src);
      *reinterpret_cast<float4*>(tile + e * FIN + f0) = x;
      float ph[4];
#pragma unroll
      for (int h = 0; h < 4; ++h) {
        float4 w = (e < E) ? wn[h] : ws[h];
        ph[h] = x.x * w.x + x.y * w.y + x.z * w.z + x.w * w.w;
      }
#pragma unroll
      for (int h = 0; h < 4; ++h) {  // quad reduce (DPP)
        ph[h] += __shfl_xor(ph[h], 1);
        ph[h] += __shfl_xor(ph[h], 2);
      }
      if ((t & 3) == 0) {
        int g = (t % TPR) >> 2;
        *reinterpret_cast<float4*>(partial + e * PSTR + g * 4) =
            make_float4(ph[0], ph[1], ph[2], ph[3]);
      }
    }
  }
  __syncthreads();
  if (t < MR * 4) {
    int e = t >> 2, h = t & 3;
    float v = 0.f;
#pragma unroll
    for (int g = 0; g < G; ++g) v += partial[e * PSTR + g * 4 + h];
    logitS[t] = v;
  }
  __syncthreads();
  if (t < 4) {
    const float es = logitS[E * 4 + t];
    float m = -1e30f;
#pragma unroll
    for (int e = 0; e < E; ++e) {
      float x = es + logitS[e * 4 + t];
      x = (x > 0.f) ? x : 0.2f * x;  // LeakyReLU(0.2)
      m = fmaxf(m, x);
    }
    float s = 0.f;
#pragma unroll
    for (int e = 0; e < E; ++e) {
      float x = es + logitS[e * 4 + t];
      x = (x > 0.f) ? x : 0.2f * x;
      float p = __expf(x - m);
      alpha[e * 4 + t] = p;
      s += p;
    }
    float inv = 1.f / s;
#pragma unroll
    for (int e = 0; e < E; ++e) alpha[e * 4 + t] *= inv;
  }
  __syncthreads();
  constexpr int C = FIN / 4;
  for (int o = t; o < 4 * C; o += 256) {
    int h = o / C, f = (o % C) * 4;
    float4 acc = make_float4(0.f, 0.f, 0.f, 0.f);
#pragma unroll
    for (int e = 0; e < E; ++e) {
      float a = alpha[e * 4 + h];
      float4 x = *reinterpret_cast<const float4*>(tile + e * FIN + f);
      acc.x = fmaf(a, x.x, acc.x);
      acc.y = fmaf(a, x.y, acc.y);
      acc.z = fmaf(a, x.z, acc.z);
      acc.w = fmaf(a, x.w, acc.w);
    }
    *reinterpret_cast<float4*>(out + h * FIN + f) = acc;
  }
}

// ======================= prepA: wa vectors + T = W1_hblk @ Wfc_hblk ===========
// blocks [0,64): T gemm (4 heads x 8 mb x 2 nb); blocks [64,84): wa naive.
__global__ void __launch_bounds__(256) prepA(
    const float* __restrict__ W0, const float* __restrict__ a0s,
    const float* __restrict__ a0n,
    const float* __restrict__ W1, const float* __restrict__ a1s,
    const float* __restrict__ a1n, const float* __restrict__ Wfc,
    float* __restrict__ wa0s, float* __restrict__ wa0n,
    float* __restrict__ wa1s, float* __restrict__ wa1n,
    float* __restrict__ T) {
  __shared__ float smem[3200];
  const int b = blockIdx.x;
  if (b < 64) {
    // T[h][k][o] = sum_m W1[k, h*128+m] * Wfc[h*128+m, o]; M=512,K=128,N=256
    int h = b >> 4, mb = (b >> 1) & 7, nb = b & 1;
    gemm_body(smem, W1 + h * 128, 512, Wfc + (size_t)h * 32768, 256,
              T + (size_t)h * 131072, 256, 128, mb * 64, nb * 128);
    return;
  }
  int idx = (b - 64) * 256 + threadIdx.x;
  if (idx >= 5120) return;
  const float* W; const float* a; float* dst; int i; int FIN;
  if (idx < 512)       { W = W0; a = a0s; dst = wa0s; i = idx;        FIN = 128; }
  else if (idx < 1024) { W = W0; a = a0n; dst = wa0n; i = idx - 512;  FIN = 128; }
  else if (idx < 3072) { W = W1; a = a1s; dst = wa1s; i = idx - 1024; FIN = 512; }
  else                 { W = W1; a = a1n; dst = wa1n; i = idx - 3072; FIN = 512; }
  int f = i >> 2, h = i & 3;
  const float* wrow = W + (size_t)f * 512 + h * 128;
  const float* arow = a + h * 128;
  float v = 0.f;
#pragma unroll 8
  for (int d = 0; d < 128; ++d) v = fmaf(wrow[d], arow[d], v);
  dst[h * FIN + f] = v;
}

// ======= fusedB: layer-0 attention (11264) + Wfinal gemm (64) + va (16) =======
__global__ void __launch_bounds__(256) fusedB(
    const float* __restrict__ h0, const float* __restrict__ h1,
    const float* __restrict__ h2, const float* __restrict__ wa0s,
    const float* __restrict__ wa0n, float* __restrict__ xagg,
    const float* __restrict__ W0, const float* __restrict__ wa1s,
    const float* __restrict__ wa1n, const float* __restrict__ T,
    float* __restrict__ va1s, float* __restrict__ va1n,
    float* __restrict__ Wfinal) {
  __shared__ float smem[4390];  // max(attn E=25: 4390, gemm: 3200)
  const int b = blockIdx.x;
  if (b < 1024) {
    gat_body<128, 32, 10>(smem, h0 + (size_t)b * 128, h1 + (size_t)b * 1280,
                          wa0s, wa0n, xagg + (size_t)b * 512);
    return;
  }
  if (b < 11264) {
    int g = b - 1024;
    gat_body<128, 32, 25>(smem, h1 + (size_t)g * 128, h2 + (size_t)g * 3200,
                          wa0s, wa0n, xagg + (size_t)b * 512);
    return;
  }
  if (b < 11264 + 64) {
    // Wfinal[h][(h0b*128+f)][o] = sum_n W0[f, h0b*128+n] * T[h][h0b*128+n][o]
    int g = b - 11264;
    int pair = g >> 2, mb = (g >> 1) & 1, nb = g & 1;
    int h = pair >> 2, h0b = pair & 3;
    gemm_body(smem, W0 + h0b * 128, 512,
              T + (size_t)h * 131072 + (size_t)h0b * 32768, 256,
              Wfinal + (size_t)h * 131072 + (size_t)h0b * 32768, 256, 128,
              mb * 64, nb * 128);
    return;
  }
  // va1: va[h*512 + h0b*128 + f] = sum_n W0[f, h0b*128+n] * wa1[h*512+h0b*128+n]
  int idx = (b - 11328) * 256 + threadIdx.x;
  if (idx >= 4096) return;
  const float* wa = (idx < 2048) ? wa1s : wa1n;
  float* dst = (idx < 2048) ? va1s : va1n;
  int i = idx & 2047;
  int h = i >> 9, h0b = (i >> 7) & 3, f = i & 127;
  const float* w0row = W0 + (size_t)f * 512 + h0b * 128;
  const float* warow = wa + h * 512 + h0b * 128;
  float v = 0.f;
#pragma unroll 8
  for (int n = 0; n < 128; ++n) v = fmaf(w0row[n], warow[n], v);
  dst[i] = v;
}

// ======================= layer 1 on xagg space ================================
__global__ void __launch_bounds__(256) gat_layer1(
    const float* __restrict__ xagg, const float* __restrict__ vaS,
    const float* __restrict__ vaN, float* __restrict__ aggx) {
  __shared__ float smem[7135];  // 11*512 + 11*129 + 44 + 40
  const int b = blockIdx.x;
  gat_body<512, 128, 10>(smem, xagg + (size_t)b * 512,
                         xagg + (size_t)(1024 + b * 10) * 512, vaS, vaN,
                         aggx + (size_t)b * 2048);
}

// ======================= tail: K-split GEMM + reduce ==========================
__global__ void __launch_bounds__(256) gemm_ksplit(
    const float* __restrict__ A, const float* __restrict__ B,
    float* __restrict__ Cpart) {
  __shared__ float smem[3200];
  const int ks = blockIdx.z;
  gemm_body(smem, A + ks * 256, 2048, B + (size_t)ks * 65536, 256,
            Cpart + (size_t)ks * 262144, 256, 256, blockIdx.x * 64,
            blockIdx.y * 128);
}

__global__ void __launch_bounds__(256) reduce8(
    const float* __restrict__ Cpart, float* __restrict__ out) {
  int i = blockIdx.x * 256 + threadIdx.x;  // float4 index, 65536 total
  const float4* p = reinterpret_cast<const float4*>(Cpart) + i;
  float4 s = p[0];
#pragma unroll
  for (int ks = 1; ks < 8; ++ks) {
    float4 v = p[(size_t)ks * 65536];
    s.x += v.x; s.y += v.y; s.z += v.z; s.w += v.w;
  }
  reinterpret_cast<float4*>(out)[i] = s;
}

extern "C" void kernel_launch(void* const* d_in, const int* in_sizes, int n_in,
                              void* d_out, int out_size, void* d_ws, size_t ws_size,
                              hipStream_t stream) {
  const float* h0  = (const float*)d_in[0];
  const float* h1  = (const float*)d_in[1];
  const float* h2  = (const float*)d_in[2];
  const float* W0  = (const float*)d_in[3];
  const float* a0s = (const float*)d_in[4];
  const float* a0n = (const float*)d_in[5];
  const float* W1  = (const float*)d_in[6];
  const float* a1s = (const float*)d_in[7];
  const float* a1n = (const float*)d_in[8];
  const float* Wfc = (const float*)d_in[9];
  float* out = (float*)d_out;

  float* ws = (float*)d_ws;
  float* wa0s   = ws;                    // [4][128]
  float* wa0n   = wa0s + 512;            // [4][128]
  float* wa1s   = wa0n + 512;            // [4][512]
  float* wa1n   = wa1s + 2048;           // [4][512]
  float* va1s   = wa1n + 2048;           // [4][4][128]
  float* va1n   = va1s + 2048;           // [4][4][128]
  float* T      = va1n + 2048;           // [4][512][256] = 524288
  float* Wfinal = T + 524288;            // [4][512][256] = 524288
  float* xaggA  = Wfinal + 524288;       // [11264][512]  = 5767168
  float* aggx   = xaggA + 11264 * 512;   // [1024][2048]  = 2097152
  float* Cpart  = aggx + 2097152;        // [8][1024][256]= 2097152
  // total ~11.0M floats = 44.1 MB

  prepA<<<84, 256, 0, stream>>>(W0, a0s, a0n, W1, a1s, a1n, Wfc,
                                wa0s, wa0n, wa1s, wa1n, T);
  fusedB<<<11344, 256, 0, stream>>>(h0, h1, h2, wa0s, wa0n, xaggA,
                                    W0, wa1s, wa1n, T, va1s, va1n, Wfinal);
  gat_layer1<<<1024, 256, 0, stream>>>(xaggA, va1s, va1n, aggx);
  gemm_ksplit<<<dim3(16, 2, 8), 256, 0, stream>>>(aggx, Wfinal, Cpart);
  reduce8<<<256, 256, 0, stream>>>(Cpart, out);
}